// Round 6
// baseline (381.786 us; speedup 1.0000x reference)
//
#include <hip/hip_runtime.h>
#include <math.h>

#define BB 4
#define QQ 200
#define NN 32
#define HWV 65536
#define NCLS 80
#define QT7 7           // ceil(200/32) q-tiles of 32
#define LN2 0.69314718055995f
#define SS 256          // k-slices per (b, qt)
#define CHUNKK 256      // k per wave
#define KT 32           // k per staged tile
#define NTI 8           // tiles per wave
#define WPB 4           // waves per block (independent k-slices, no barriers)

typedef __bf16 bf16x8 __attribute__((ext_vector_type(8)));
typedef __bf16 bf16x4 __attribute__((ext_vector_type(4)));
typedef float f32x16 __attribute__((ext_vector_type(16)));
typedef float f32x4 __attribute__((ext_vector_type(4)));

__device__ __forceinline__ float bflo(unsigned u) {
  union { unsigned i; float f; } c; c.i = u << 16; return c.f;
}
__device__ __forceinline__ float bfhi(unsigned u) {
  union { unsigned i; float f; } c; c.i = u & 0xffff0000u; return c.f;
}

// ---------------- main MFMA kernel, coalesced LDS-staged ----------------
// grid (SS/WPB, QT7, BB), 256 threads. Each wave = one k-slice of 256,
// 32q x 32n output tile, fully independent (no __syncthreads anywhere).
__global__ __launch_bounds__(256, 3) void main_kernel(
    const float* __restrict__ pred_masks, const float* __restrict__ gt_masks,
    __bf16* __restrict__ pD, __bf16* __restrict__ pS, float* __restrict__ pQs,
    float* __restrict__ pT) {
  // d in 16B-units 0..3, s in units 4..7 of each 128B row; unit ^= (row&7)
  __shared__ __bf16 ds_tile[WPB][32][64];   // 16 KB
  // t as f32, rows 128B; content source-swizzled so LDS stays linear for gll
  __shared__ float t_lds[WPB][2][32][32];   // 32 KB, double-buffered

  const int tid = threadIdx.x;
  const int w = tid >> 6, lane = tid & 63;
  const int sIdx = blockIdx.x * WPB + w;
  const int qt = blockIdx.y, b = blockIdx.z;
  const int rc = lane & 31, half = lane >> 5;
  const int h8 = lane >> 3, c8 = lane & 7;   // staging: 8 rows x 8 col-groups
  const bool doT = (qt == 0);
  const int k0 = sIdx * CHUNKK;

  // staging pointers: call j covers rows 8j+h8
  const float* pA[4];
  const float* pT4[4];
#pragma unroll
  for (int j = 0; j < 4; ++j) {
    int ar = qt * 32 + 8 * j + h8;
    if (ar > QQ - 1) ar = QQ - 1;            // pad rows duplicate row 199
    pA[j] = pred_masks + ((size_t)b * QQ + ar) * HWV + k0 + 4 * c8;
    // source pre-swizzle: LDS[row][u] will hold global[row][u ^ (row&7)]
    pT4[j] = gt_masks + ((size_t)b * NN + (8 * j + h8)) * HWV + k0 + 4 * (c8 ^ h8);
  }

  char* dsb = (char*)&ds_tile[w][0][0];
  const int wrow = h8 * 128;                                  // + j*1024 per call
  const int woff_d = 16 * ((c8 >> 1) ^ h8) + 8 * (c8 & 1);    // d write byte
  const int woff_s = 16 * (((c8 >> 1) + 4) ^ h8) + 8 * (c8 & 1);

  f32x16 accD, accS;
#pragma unroll
  for (int r = 0; r < 16; ++r) { accD[r] = 0.f; accS[r] = 0.f; }
  float ssj[4] = {0.f, 0.f, 0.f, 0.f};   // per row-group sums of sigmoid
  float xsj[4] = {0.f, 0.f, 0.f, 0.f};   // sums of x
  float lgj[4] = {0.f, 0.f, 0.f, 0.f};   // sums of log2(1+e^-x)
  float tl = 0.f;

  f32x4 a[4], an[4];
  // prologue: issue A(0) and t(0)
#pragma unroll
  for (int j = 0; j < 4; ++j) a[j] = *reinterpret_cast<const f32x4*>(pA[j]);
#pragma unroll
  for (int j = 0; j < 4; ++j)
    __builtin_amdgcn_global_load_lds(
        (const __attribute__((address_space(1))) void*)(pT4[j]),
        (__attribute__((address_space(3))) void*)(&t_lds[w][0][8 * j][0]),
        16, 0, 0);

#pragma unroll
  for (int tile = 0; tile < NTI; ++tile) {
    const int cur = tile & 1;
    // 1. issue next tile's A loads + t gll (keeps 8 vmem ops in flight)
    if (tile + 1 < NTI) {
      const int koff = (tile + 1) * KT;
#pragma unroll
      for (int j = 0; j < 4; ++j)
        an[j] = *reinterpret_cast<const f32x4*>(pA[j] + koff);
#pragma unroll
      for (int j = 0; j < 4; ++j)
        __builtin_amdgcn_global_load_lds(
            (const __attribute__((address_space(1))) void*)(pT4[j] + koff),
            (__attribute__((address_space(3))) void*)(&t_lds[w][cur ^ 1][8 * j][0]),
            16, 0, 0);
    }
    // 2. transform current A (compiler inserts counted vmcnt for a[] regs)
#pragma unroll
    for (int j = 0; j < 4; ++j) {
      f32x4 x = a[j];
      float e0 = __expf(-x.x), e1 = __expf(-x.y), e2 = __expf(-x.z), e3 = __expf(-x.w);
      float a0 = 1.f + e0, a1 = 1.f + e1, a2 = 1.f + e2, a3 = 1.f + e3;
      float i0 = __builtin_amdgcn_rcpf(a0), i1 = __builtin_amdgcn_rcpf(a1);
      float i2 = __builtin_amdgcn_rcpf(a2), i3 = __builtin_amdgcn_rcpf(a3);
      ssj[j] += (i0 + i1) + (i2 + i3);
      xsj[j] += (x.x + x.y) + (x.z + x.w);
      lgj[j] += __log2f((a0 * a1) * (a2 * a3));  // |x|<~6 -> prod4 < 2e10, safe
      bf16x4 dv = {(__bf16)x.x, (__bf16)x.y, (__bf16)x.z, (__bf16)x.w};
      bf16x4 sv = {(__bf16)i0, (__bf16)i1, (__bf16)i2, (__bf16)i3};
      *reinterpret_cast<bf16x4*>(dsb + j * 1024 + wrow + woff_d) = dv;
      *reinterpret_cast<bf16x4*>(dsb + j * 1024 + wrow + woff_s) = sv;
    }
    // 3. ensure t(tile) gll landed; keep the 8 next-tile ops in flight
    if (tile + 1 < NTI) {
      asm volatile("s_waitcnt vmcnt(8)" ::: "memory");
    } else {
      asm volatile("s_waitcnt vmcnt(0)" ::: "memory");
    }
    // 4. fragments + MFMA (lgkmcnt for ds_write->ds_read handled by compiler)
    const char* tb = (const char*)&t_lds[w][cur][0][0];
#pragma unroll
    for (int m = 0; m < 2; ++m) {
      int ud = (2 * m + half) ^ (rc & 7);
      int us = ((2 * m + half) + 4) ^ (rc & 7);
      bf16x8 df = *reinterpret_cast<const bf16x8*>(dsb + rc * 128 + 16 * ud);
      bf16x8 sf = *reinterpret_cast<const bf16x8*>(dsb + rc * 128 + 16 * us);
      int v0 = 4 * m + 2 * half;
      f32x4 t0 = *reinterpret_cast<const f32x4*>(tb + rc * 128 + 16 * (v0 ^ (rc & 7)));
      f32x4 t1 = *reinterpret_cast<const f32x4*>(tb + rc * 128 + 16 * ((v0 + 1) ^ (rc & 7)));
      if (doT) tl += ((t0.x + t0.y) + (t0.z + t0.w)) + ((t1.x + t1.y) + (t1.z + t1.w));
      bf16x8 tf = {(__bf16)t0.x, (__bf16)t0.y, (__bf16)t0.z, (__bf16)t0.w,
                   (__bf16)t1.x, (__bf16)t1.y, (__bf16)t1.z, (__bf16)t1.w};
      accD = __builtin_amdgcn_mfma_f32_32x32x16_bf16(df, tf, accD, 0, 0, 0);
      accS = __builtin_amdgcn_mfma_f32_32x32x16_bf16(sf, tf, accS, 0, 0, 0);
    }
#pragma unroll
    for (int j = 0; j < 4; ++j) a[j] = an[j];
  }

  // row sums: reduce across the 8 col-group lanes of each row
#pragma unroll
  for (int j = 0; j < 4; ++j) {
#pragma unroll
    for (int msk = 1; msk <= 4; msk <<= 1) {
      ssj[j] += __shfl_xor(ssj[j], msk);
      xsj[j] += __shfl_xor(xsj[j], msk);
      lgj[j] += __shfl_xor(lgj[j], msk);
    }
  }
  const size_t tile32 = (size_t)(b * QT7 + qt);
  if (c8 == 0) {
#pragma unroll
    for (int j = 0; j < 4; ++j) {
      int row = 8 * j + h8;
      float* pq = pQs + ((tile32 * 32 + row) * (size_t)SS + sIdx) * 2;
      pq[0] = ssj[j];                       // sum of sigmoid over slice
      pq[1] = -xsj[j] - LN2 * lgj[j];       // sum of log(1-sigmoid)
    }
  }
  if (doT) {
    tl += __shfl_xor(tl, 32);
    if (lane < 32) pT[((size_t)b * SS + sIdx) * NN + rc] = tl;
  }
#pragma unroll
  for (int r = 0; r < 16; ++r) {
    int row = (r & 3) + 8 * (r >> 2) + 4 * half;   // verified C/D map
    size_t o = ((tile32 * 32 + row) * (size_t)SS + sIdx) * 32 + rc;  // [q][s][n]
    pD[o] = (__bf16)accD[r];
    pS[o] = (__bf16)accS[r];
  }
}

// ---------------- reduce t partials ----------------
__global__ __launch_bounds__(64) void treduce_kernel(const float* __restrict__ pT,
                                                     float* __restrict__ tsum) {
  int b = blockIdx.x;
  int n = threadIdx.x & 31, sg = threadIdx.x >> 5;
  float acc = 0.f;
  for (int s = sg; s < SS; s += 2) acc += pT[((size_t)b * SS + s) * NN + n];
  acc += __shfl_xor(acc, 32);
  if (threadIdx.x < 32) tsum[b * NN + n] = acc;
}

// ---------------- reduce + combine ----------------
__global__ __launch_bounds__(256) void combine_kernel(
    const float* __restrict__ pred_logits, const int* __restrict__ gt_classes,
    const __bf16* __restrict__ pD, const __bf16* __restrict__ pS,
    const float* __restrict__ pQs, const float* __restrict__ tsum,
    float* __restrict__ out) {
  __shared__ float redD[32][33];
  __shared__ float redS[32][33];
  __shared__ float redQ[4][2];
  int bq = blockIdx.x;
  int b = bq / QQ, q = bq % QQ;
  int qt = q >> 5, qi = q & 31;
  int tid = threadIdx.x;
  int sg = tid >> 3, nq = tid & 7;  // 32 s-groups x 8 n-quads
  size_t rowbase = ((size_t)(b * QT7 + qt) * 32 + qi) * (size_t)SS;
  float dD[4] = {0.f, 0.f, 0.f, 0.f}, dS4[4] = {0.f, 0.f, 0.f, 0.f};
  for (int s = sg; s < SS; s += 32) {
    size_t o = (rowbase + s) * 32 + nq * 4;
    uint2 ud = *reinterpret_cast<const uint2*>(pD + o);
    uint2 us = *reinterpret_cast<const uint2*>(pS + o);
    dD[0] += bflo(ud.x); dD[1] += bfhi(ud.x); dD[2] += bflo(ud.y); dD[3] += bfhi(ud.y);
    dS4[0] += bflo(us.x); dS4[1] += bfhi(us.x); dS4[2] += bflo(us.y); dS4[3] += bfhi(us.y);
  }
#pragma unroll
  for (int j = 0; j < 4; ++j) {
    redD[sg][nq * 4 + j] = dD[j];
    redS[sg][nq * 4 + j] = dS4[j];
  }
  float sS = 0.f, sL = 0.f;
  for (int s = tid; s < SS; s += 256) {
    const float* pq = pQs + (rowbase + s) * 2;
    sS += pq[0];
    sL += pq[1];
  }
#pragma unroll
  for (int m = 1; m < 64; m <<= 1) { sS += __shfl_xor(sS, m); sL += __shfl_xor(sL, m); }
  if ((tid & 63) == 0) { redQ[tid >> 6][0] = sS; redQ[tid >> 6][1] = sL; }
  __syncthreads();
  if (tid < 32) {
    int n = tid;
    float tD = 0.f, tS = 0.f;
#pragma unroll 8
    for (int g = 0; g < 32; ++g) { tD += redD[g][n]; tS += redS[g][n]; }
    float fsS = (redQ[0][0] + redQ[1][0]) + (redQ[2][0] + redQ[3][0]);
    float fsL = (redQ[0][1] + redQ[1][1]) + (redQ[2][1] + redQ[3][1]);
    int cls = gt_classes[b * NN + n];
    float logit = pred_logits[((size_t)(b * QQ + q)) * NCLS + cls];
    float prob = 1.f / (1.f + __expf(-logit));
    float bce = -(tD + fsL) * (1.f / (float)HWV);
    float dice = 1.f - 2.f * tS / (fsS + tsum[b * NN + n] + 1e-6f);
    float c = -prob + 5.f * bce + 5.f * dice;
    if (!isfinite(c)) c = 10000.f;
    out[(size_t)bq * NN + n] = c;
  }
}

extern "C" void kernel_launch(void* const* d_in, const int* in_sizes, int n_in,
                              void* d_out, int out_size, void* d_ws, size_t ws_size,
                              hipStream_t stream) {
  const float* pred_logits = (const float*)d_in[0];
  const float* pred_masks  = (const float*)d_in[1];
  const int*   gt_classes  = (const int*)d_in[2];
  const float* gt_masks    = (const float*)d_in[3];
  float* out = (float*)d_out;

  // workspace: ~31 MB (ws proved >= 62 MB in round 5)
  __bf16* pD = (__bf16*)d_ws;
  __bf16* pS = pD + (size_t)BB * QT7 * SS * 1024;
  float* pQs = (float*)(pS + (size_t)BB * QT7 * SS * 1024);
  float* pT = pQs + (size_t)BB * QT7 * 32 * SS * 2;
  float* tsum = pT + (size_t)BB * SS * NN;

  main_kernel<<<dim3(SS / WPB, QT7, BB), WPB * 64, 0, stream>>>(
      pred_masks, gt_masks, pD, pS, pQs, pT);
  treduce_kernel<<<BB, 64, 0, stream>>>(pT, tsum);
  combine_kernel<<<BB * QQ, 256, 0, stream>>>(pred_logits, gt_classes, pD, pS, pQs,
                                              tsum, out);
}

// Round 7
// 311.030 us; speedup vs baseline: 1.2275x; 1.2275x over previous
//
#include <hip/hip_runtime.h>
#include <math.h>

#define BB 4
#define QQ 200
#define NN 32
#define HWV 65536
#define NCLS 80
#define QT7 7           // ceil(200/32) q-tiles of 32
#define LN2 0.69314718055995f
#define SS 256          // k-slices per (b, qt)
#define CHUNKK 256      // k per wave
#define KT 64           // k per staged tile
#define NT 4            // tiles per wave
#define WPB 4           // waves per block (independent k-slices, no barriers)
#define LDH 72          // bf16 per LDS row: 64 data + 8 pad -> 144B stride (9x16B, conflict-minimal)

typedef __bf16 bf16x8 __attribute__((ext_vector_type(8)));
typedef __bf16 bf16x4 __attribute__((ext_vector_type(4)));
typedef float f32x16 __attribute__((ext_vector_type(16)));
typedef float f32x4 __attribute__((ext_vector_type(4)));

__device__ __forceinline__ float bflo(unsigned u) {
  union { unsigned i; float f; } c; c.i = u << 16; return c.f;
}
__device__ __forceinline__ float bfhi(unsigned u) {
  union { unsigned i; float f; } c; c.i = u & 0xffff0000u; return c.f;
}

// ---------------- main MFMA kernel, coalesced reg->LDS staged ----------------
// grid (SS/WPB, QT7, BB), 256 threads. Each wave = one k-slice of 256 for a
// 32q x 32n tile; waves fully independent (no __syncthreads).
// Global loads: 1KB/instr = 4 rows x 256B contiguous (16 consecutive lines in
// 4 streams) -- avoids the 32x256KB same-channel scatter of the direct path.
__global__ __launch_bounds__(256, 3) void main_kernel(
    const float* __restrict__ pred_masks, const float* __restrict__ gt_masks,
    __bf16* __restrict__ pD, __bf16* __restrict__ pS, float* __restrict__ pQs,
    float* __restrict__ pT) {
  __shared__ __bf16 xls[WPB][32][LDH];   // 4.6 KB/wave
  __shared__ __bf16 tls[WPB][32][LDH];   // 4.6 KB/wave

  const int tid = threadIdx.x;
  const int w = tid >> 6, lane = tid & 63;
  const int sIdx = blockIdx.x * WPB + w;
  const int qt = blockIdx.y, b = blockIdx.z;
  const int rc = lane & 31, half = lane >> 5;
  const int r4 = lane >> 4, l16 = lane & 15;   // staging: 4 rows x 16 chunks
  const bool doT = (qt == 0);
  const int k0 = sIdx * CHUNKK;

  // byte offsets: row stride = HWV*4B = 1<<18
  const char* baseA = (const char*)(pred_masks + (size_t)b * QQ * HWV + k0 + l16 * 4);
  const char* baseT = (const char*)(gt_masks + (size_t)b * NN * HWV + k0 + l16 * 4);
  unsigned aoff[8];
#pragma unroll
  for (int i = 0; i < 8; ++i) {
    int ar = qt * 32 + 4 * i + r4;
    if (ar > QQ - 1) ar = QQ - 1;        // pad rows duplicate row 199 (discarded)
    aoff[i] = (unsigned)ar << 18;
  }

  f32x16 accD, accS;
#pragma unroll
  for (int r = 0; r < 16; ++r) { accD[r] = 0.f; accS[r] = 0.f; }
  float ssum = 0.f, xsum = 0.f, lgsum = 0.f, tsl = 0.f;

  f32x4 av[8], tv[8];
  auto LOADT = [&](int tt) {
#pragma unroll
    for (int i = 0; i < 8; ++i)
      av[i] = __builtin_nontemporal_load(
          reinterpret_cast<const f32x4*>(baseA + aoff[i] + tt * (KT * 4)));
#pragma unroll
    for (int i = 0; i < 8; ++i)
      tv[i] = *reinterpret_cast<const f32x4*>(
          baseT + ((unsigned)(4 * i + r4) << 18) + tt * (KT * 4));
  };

  LOADT(0);
#pragma unroll
  for (int tt = 0; tt < NT; ++tt) {
    // ---- stage current tile (consumes av/tv; waits counted vmcnt) ----
#pragma unroll
    for (int i = 0; i < 8; ++i) {
      int r = 4 * i + r4;
      f32x4 x = av[i];
      bf16x4 xv = {(__bf16)x.x, (__bf16)x.y, (__bf16)x.z, (__bf16)x.w};
      *reinterpret_cast<bf16x4*>(&xls[w][r][l16 * 4]) = xv;
      f32x4 t = tv[i];
      bf16x4 tv4 = {(__bf16)t.x, (__bf16)t.y, (__bf16)t.z, (__bf16)t.w};
      *reinterpret_cast<bf16x4*>(&tls[w][r][l16 * 4]) = tv4;
    }
    // ---- immediately reissue loads for next tile (in flight during compute) ----
    if (tt + 1 < NT) LOADT(tt + 1);
    // ---- fragments + transform + MFMA (LDS ops in-order per wave) ----
    const char* xb = (const char*)&xls[w][0][0];
    const char* tb = (const char*)&tls[w][0][0];
#pragma unroll
    for (int ks = 0; ks < 4; ++ks) {
      int off = rc * (LDH * 2) + ks * 32 + half * 16;
      bf16x8 xf = *reinterpret_cast<const bf16x8*>(xb + off);
      bf16x8 tf = *reinterpret_cast<const bf16x8*>(tb + off);
      bf16x8 sf;
      float p0 = 1.f, p1 = 1.f;
#pragma unroll
      for (int j = 0; j < 8; ++j) {
        float x = (float)xf[j];
        float e = __expf(-x);                  // |x| <~ 6 for N(0,1) inputs
        float a = 1.f + e;
        float s = __builtin_amdgcn_rcpf(a);    // sigmoid(x)
        sf[j] = (__bf16)s;
        ssum += s;
        xsum += x;
        if (j < 4) p0 *= a; else p1 *= a;      // two chains for ILP
      }
      lgsum += __log2f(p0 * p1);               // prod8 < 3e20, fp32-safe
      if (doT) {
#pragma unroll
        for (int j = 0; j < 8; ++j) tsl += (float)tf[j];
      }
      accD = __builtin_amdgcn_mfma_f32_32x32x16_bf16(xf, tf, accD, 0, 0, 0);
      accS = __builtin_amdgcn_mfma_f32_32x32x16_bf16(sf, tf, accS, 0, 0, 0);
    }
  }

  // lanes l, l^32 hold the two k-halves of row rc
  ssum += __shfl_xor(ssum, 32);
  xsum += __shfl_xor(xsum, 32);
  lgsum += __shfl_xor(lgsum, 32);

  const size_t tile32 = (size_t)(b * QT7 + qt);
  if (lane < 32) {
    float* pq = pQs + ((tile32 * 32 + rc) * (size_t)SS + sIdx) * 2;
    pq[0] = ssum;                       // sum of sigmoid over slice
    pq[1] = -xsum - LN2 * lgsum;        // sum of log(1-sigmoid)
  }
  if (doT) {
    tsl += __shfl_xor(tsl, 32);
    if (lane < 32) pT[((size_t)b * SS + sIdx) * NN + rc] = tsl;
  }
#pragma unroll
  for (int r = 0; r < 16; ++r) {
    int row = (r & 3) + 8 * (r >> 2) + 4 * half;   // verified C/D map
    size_t o = ((tile32 * 32 + row) * (size_t)SS + sIdx) * 32 + rc;  // [q][s][n]
    pD[o] = (__bf16)accD[r];
    pS[o] = (__bf16)accS[r];
  }
}

// ---------------- reduce t partials ----------------
__global__ __launch_bounds__(64) void treduce_kernel(const float* __restrict__ pT,
                                                     float* __restrict__ tsum) {
  int b = blockIdx.x;
  int n = threadIdx.x & 31, sg = threadIdx.x >> 5;
  float acc = 0.f;
  for (int s = sg; s < SS; s += 2) acc += pT[((size_t)b * SS + s) * NN + n];
  acc += __shfl_xor(acc, 32);
  if (threadIdx.x < 32) tsum[b * NN + n] = acc;
}

// ---------------- reduce + combine ----------------
__global__ __launch_bounds__(256) void combine_kernel(
    const float* __restrict__ pred_logits, const int* __restrict__ gt_classes,
    const __bf16* __restrict__ pD, const __bf16* __restrict__ pS,
    const float* __restrict__ pQs, const float* __restrict__ tsum,
    float* __restrict__ out) {
  __shared__ float redD[32][33];
  __shared__ float redS[32][33];
  __shared__ float redQ[4][2];
  int bq = blockIdx.x;
  int b = bq / QQ, q = bq % QQ;
  int qt = q >> 5, qi = q & 31;
  int tid = threadIdx.x;
  int sg = tid >> 3, nq = tid & 7;  // 32 s-groups x 8 n-quads
  size_t rowbase = ((size_t)(b * QT7 + qt) * 32 + qi) * (size_t)SS;
  float dD[4] = {0.f, 0.f, 0.f, 0.f}, dS4[4] = {0.f, 0.f, 0.f, 0.f};
  for (int s = sg; s < SS; s += 32) {
    size_t o = (rowbase + s) * 32 + nq * 4;
    uint2 ud = *reinterpret_cast<const uint2*>(pD + o);
    uint2 us = *reinterpret_cast<const uint2*>(pS + o);
    dD[0] += bflo(ud.x); dD[1] += bfhi(ud.x); dD[2] += bflo(ud.y); dD[3] += bfhi(ud.y);
    dS4[0] += bflo(us.x); dS4[1] += bfhi(us.x); dS4[2] += bflo(us.y); dS4[3] += bfhi(us.y);
  }
#pragma unroll
  for (int j = 0; j < 4; ++j) {
    redD[sg][nq * 4 + j] = dD[j];
    redS[sg][nq * 4 + j] = dS4[j];
  }
  float sS = 0.f, sL = 0.f;
  for (int s = tid; s < SS; s += 256) {
    const float* pq = pQs + (rowbase + s) * 2;
    sS += pq[0];
    sL += pq[1];
  }
#pragma unroll
  for (int m = 1; m < 64; m <<= 1) { sS += __shfl_xor(sS, m); sL += __shfl_xor(sL, m); }
  if ((tid & 63) == 0) { redQ[tid >> 6][0] = sS; redQ[tid >> 6][1] = sL; }
  __syncthreads();
  if (tid < 32) {
    int n = tid;
    float tD = 0.f, tS = 0.f;
#pragma unroll 8
    for (int g = 0; g < 32; ++g) { tD += redD[g][n]; tS += redS[g][n]; }
    float fsS = (redQ[0][0] + redQ[1][0]) + (redQ[2][0] + redQ[3][0]);
    float fsL = (redQ[0][1] + redQ[1][1]) + (redQ[2][1] + redQ[3][1]);
    int cls = gt_classes[b * NN + n];
    float logit = pred_logits[((size_t)(b * QQ + q)) * NCLS + cls];
    float prob = 1.f / (1.f + __expf(-logit));
    float bce = -(tD + fsL) * (1.f / (float)HWV);
    float dice = 1.f - 2.f * tS / (fsS + tsum[b * NN + n] + 1e-6f);
    float c = -prob + 5.f * bce + 5.f * dice;
    if (!isfinite(c)) c = 10000.f;
    out[(size_t)bq * NN + n] = c;
  }
}

extern "C" void kernel_launch(void* const* d_in, const int* in_sizes, int n_in,
                              void* d_out, int out_size, void* d_ws, size_t ws_size,
                              hipStream_t stream) {
  const float* pred_logits = (const float*)d_in[0];
  const float* pred_masks  = (const float*)d_in[1];
  const int*   gt_classes  = (const int*)d_in[2];
  const float* gt_masks    = (const float*)d_in[3];
  float* out = (float*)d_out;

  // workspace: ~31 MB
  __bf16* pD = (__bf16*)d_ws;
  __bf16* pS = pD + (size_t)BB * QT7 * SS * 1024;
  float* pQs = (float*)(pS + (size_t)BB * QT7 * SS * 1024);
  float* pT = pQs + (size_t)BB * QT7 * 32 * SS * 2;
  float* tsum = pT + (size_t)BB * SS * NN;

  main_kernel<<<dim3(SS / WPB, QT7, BB), WPB * 64, 0, stream>>>(
      pred_masks, gt_masks, pD, pS, pQs, pT);
  treduce_kernel<<<BB, 64, 0, stream>>>(pT, tsum);
  combine_kernel<<<BB * QQ, 256, 0, stream>>>(pred_logits, gt_classes, pD, pS, pQs,
                                              tsum, out);
}

// Round 8
// 238.085 us; speedup vs baseline: 1.6036x; 1.3064x over previous
//
#include <hip/hip_runtime.h>
#include <math.h>

#define BB 4
#define QQ 200
#define NN 32
#define HWV 65536
#define NCLS 80
#define QT7 7           // ceil(200/32) q-tiles of 32
#define LN2 0.69314718055995f
#define SS 256          // k-slices per (b, qt)
#define CHUNKK 256      // k per wave
#define KT 64           // k per staged tile
#define NT 4            // tiles per wave
#define WPB 4           // waves per block (independent k-slices, no barriers)
#define LDH 72          // bf16 per LDS row: 64 data + 8 pad -> 144B stride (9x16B, conflict-minimal)

typedef __bf16 bf16x8 __attribute__((ext_vector_type(8)));
typedef __bf16 bf16x4 __attribute__((ext_vector_type(4)));
typedef float f32x16 __attribute__((ext_vector_type(16)));
typedef float f32x4 __attribute__((ext_vector_type(4)));

__device__ __forceinline__ float bflo(unsigned u) {
  union { unsigned i; float f; } c; c.i = u << 16; return c.f;
}
__device__ __forceinline__ float bfhi(unsigned u) {
  union { unsigned i; float f; } c; c.i = u & 0xffff0000u; return c.f;
}

// ---------------- main MFMA kernel, coalesced reg->LDS staged ----------------
// grid (SS/WPB, QT7, BB), 256 threads. Each wave = one k-slice of 256 for a
// 32q x 32n tile; waves fully independent (no __syncthreads).
// __launch_bounds__(256, 2): 256-VGPR cap -> ~130-reg live set fits, NO SPILLS
// (r6/r7 used (256,3) -> 84-reg clamp -> 400+ MB scratch traffic).
__global__ __launch_bounds__(256, 2) void main_kernel(
    const float* __restrict__ pred_masks, const float* __restrict__ gt_masks,
    __bf16* __restrict__ pD, __bf16* __restrict__ pS, float* __restrict__ pQs,
    float* __restrict__ pT) {
  __shared__ __bf16 xls[WPB][32][LDH];   // 4.6 KB/wave
  __shared__ __bf16 tls[WPB][32][LDH];   // 4.6 KB/wave

  const int tid = threadIdx.x;
  const int w = tid >> 6, lane = tid & 63;
  const int sIdx = blockIdx.x * WPB + w;
  const int qt = blockIdx.y, b = blockIdx.z;
  const int rc = lane & 31, half = lane >> 5;
  const int r4 = lane >> 4, l16 = lane & 15;   // staging: 4 rows x 16 chunks
  const bool doT = (qt == 0);
  const int k0 = sIdx * CHUNKK;

  // byte offsets: row stride = HWV*4B = 1<<18
  const char* baseA = (const char*)(pred_masks + (size_t)b * QQ * HWV + k0 + l16 * 4);
  const char* baseT = (const char*)(gt_masks + (size_t)b * NN * HWV + k0 + l16 * 4);
  unsigned aoff[8];
#pragma unroll
  for (int i = 0; i < 8; ++i) {
    int ar = qt * 32 + 4 * i + r4;
    if (ar > QQ - 1) ar = QQ - 1;        // pad rows duplicate row 199 (discarded)
    aoff[i] = (unsigned)ar << 18;
  }

  f32x16 accD, accS;
#pragma unroll
  for (int r = 0; r < 16; ++r) { accD[r] = 0.f; accS[r] = 0.f; }
  float ssum = 0.f, xsum = 0.f, lgsum = 0.f, tsl = 0.f;

  f32x4 av[8], tv[8];
  auto LOADT = [&](int tt) {
#pragma unroll
    for (int i = 0; i < 8; ++i)
      av[i] = __builtin_nontemporal_load(
          reinterpret_cast<const f32x4*>(baseA + aoff[i] + tt * (KT * 4)));
#pragma unroll
    for (int i = 0; i < 8; ++i)
      tv[i] = *reinterpret_cast<const f32x4*>(
          baseT + ((unsigned)(4 * i + r4) << 18) + tt * (KT * 4));
  };

  LOADT(0);
#pragma unroll
  for (int tt = 0; tt < NT; ++tt) {
    // ---- stage current tile (consumes av/tv; compiler inserts counted vmcnt) ----
#pragma unroll
    for (int i = 0; i < 8; ++i) {
      int r = 4 * i + r4;
      f32x4 x = av[i];
      bf16x4 xv = {(__bf16)x.x, (__bf16)x.y, (__bf16)x.z, (__bf16)x.w};
      *reinterpret_cast<bf16x4*>(&xls[w][r][l16 * 4]) = xv;
      f32x4 t = tv[i];
      bf16x4 tv4 = {(__bf16)t.x, (__bf16)t.y, (__bf16)t.z, (__bf16)t.w};
      *reinterpret_cast<bf16x4*>(&tls[w][r][l16 * 4]) = tv4;
    }
    // ---- immediately reissue loads for next tile (in flight during compute) ----
    if (tt + 1 < NT) LOADT(tt + 1);
    // ---- fragments + transform + MFMA (LDS ops in-order per wave) ----
    const char* xb = (const char*)&xls[w][0][0];
    const char* tb = (const char*)&tls[w][0][0];
#pragma unroll
    for (int ks = 0; ks < 4; ++ks) {
      int off = rc * (LDH * 2) + ks * 32 + half * 16;
      bf16x8 xf = *reinterpret_cast<const bf16x8*>(xb + off);
      bf16x8 tf = *reinterpret_cast<const bf16x8*>(tb + off);
      bf16x8 sf;
      float p0 = 1.f, p1 = 1.f;
#pragma unroll
      for (int j = 0; j < 8; ++j) {
        float x = (float)xf[j];
        float e = __expf(-x);                  // |x| <~ 6 for N(0,1) inputs
        float a = 1.f + e;
        float s = __builtin_amdgcn_rcpf(a);    // sigmoid(x)
        sf[j] = (__bf16)s;
        ssum += s;
        xsum += x;
        if (j < 4) p0 *= a; else p1 *= a;      // two chains for ILP
      }
      lgsum += __log2f(p0 * p1);               // prod8 < 3e20, fp32-safe
      if (doT) {
#pragma unroll
        for (int j = 0; j < 8; ++j) tsl += (float)tf[j];
      }
      accD = __builtin_amdgcn_mfma_f32_32x32x16_bf16(xf, tf, accD, 0, 0, 0);
      accS = __builtin_amdgcn_mfma_f32_32x32x16_bf16(sf, tf, accS, 0, 0, 0);
    }
  }

  // lanes l, l^32 hold the two k-halves of row rc
  ssum += __shfl_xor(ssum, 32);
  xsum += __shfl_xor(xsum, 32);
  lgsum += __shfl_xor(lgsum, 32);

  const size_t tile32 = (size_t)(b * QT7 + qt);
  if (lane < 32) {
    float* pq = pQs + ((tile32 * 32 + rc) * (size_t)SS + sIdx) * 2;
    pq[0] = ssum;                       // sum of sigmoid over slice
    pq[1] = -xsum - LN2 * lgsum;        // sum of log(1-sigmoid)
  }
  if (doT) {
    tsl += __shfl_xor(tsl, 32);
    if (lane < 32) pT[((size_t)b * SS + sIdx) * NN + rc] = tsl;
  }
#pragma unroll
  for (int r = 0; r < 16; ++r) {
    int row = (r & 3) + 8 * (r >> 2) + 4 * half;   // verified C/D map
    size_t o = ((tile32 * 32 + row) * (size_t)SS + sIdx) * 32 + rc;  // [q][s][n]
    pD[o] = (__bf16)accD[r];
    pS[o] = (__bf16)accS[r];
  }
}

// ---------------- reduce t partials ----------------
__global__ __launch_bounds__(64) void treduce_kernel(const float* __restrict__ pT,
                                                     float* __restrict__ tsum) {
  int b = blockIdx.x;
  int n = threadIdx.x & 31, sg = threadIdx.x >> 5;
  float acc = 0.f;
  for (int s = sg; s < SS; s += 2) acc += pT[((size_t)b * SS + s) * NN + n];
  acc += __shfl_xor(acc, 32);
  if (threadIdx.x < 32) tsum[b * NN + n] = acc;
}

// ---------------- reduce + combine ----------------
__global__ __launch_bounds__(256) void combine_kernel(
    const float* __restrict__ pred_logits, const int* __restrict__ gt_classes,
    const __bf16* __restrict__ pD, const __bf16* __restrict__ pS,
    const float* __restrict__ pQs, const float* __restrict__ tsum,
    float* __restrict__ out) {
  __shared__ float redD[32][33];
  __shared__ float redS[32][33];
  __shared__ float redQ[4][2];
  int bq = blockIdx.x;
  int b = bq / QQ, q = bq % QQ;
  int qt = q >> 5, qi = q & 31;
  int tid = threadIdx.x;
  int sg = tid >> 3, nq = tid & 7;  // 32 s-groups x 8 n-quads
  size_t rowbase = ((size_t)(b * QT7 + qt) * 32 + qi) * (size_t)SS;
  float dD[4] = {0.f, 0.f, 0.f, 0.f}, dS4[4] = {0.f, 0.f, 0.f, 0.f};
  for (int s = sg; s < SS; s += 32) {
    size_t o = (rowbase + s) * 32 + nq * 4;
    uint2 ud = *reinterpret_cast<const uint2*>(pD + o);
    uint2 us = *reinterpret_cast<const uint2*>(pS + o);
    dD[0] += bflo(ud.x); dD[1] += bfhi(ud.x); dD[2] += bflo(ud.y); dD[3] += bfhi(ud.y);
    dS4[0] += bflo(us.x); dS4[1] += bfhi(us.x); dS4[2] += bflo(us.y); dS4[3] += bfhi(us.y);
  }
#pragma unroll
  for (int j = 0; j < 4; ++j) {
    redD[sg][nq * 4 + j] = dD[j];
    redS[sg][nq * 4 + j] = dS4[j];
  }
  float sS = 0.f, sL = 0.f;
  for (int s = tid; s < SS; s += 256) {
    const float* pq = pQs + (rowbase + s) * 2;
    sS += pq[0];
    sL += pq[1];
  }
#pragma unroll
  for (int m = 1; m < 64; m <<= 1) { sS += __shfl_xor(sS, m); sL += __shfl_xor(sL, m); }
  if ((tid & 63) == 0) { redQ[tid >> 6][0] = sS; redQ[tid >> 6][1] = sL; }
  __syncthreads();
  if (tid < 32) {
    int n = tid;
    float tD = 0.f, tS = 0.f;
#pragma unroll 8
    for (int g = 0; g < 32; ++g) { tD += redD[g][n]; tS += redS[g][n]; }
    float fsS = (redQ[0][0] + redQ[1][0]) + (redQ[2][0] + redQ[3][0]);
    float fsL = (redQ[0][1] + redQ[1][1]) + (redQ[2][1] + redQ[3][1]);
    int cls = gt_classes[b * NN + n];
    float logit = pred_logits[((size_t)(b * QQ + q)) * NCLS + cls];
    float prob = 1.f / (1.f + __expf(-logit));
    float bce = -(tD + fsL) * (1.f / (float)HWV);
    float dice = 1.f - 2.f * tS / (fsS + tsum[b * NN + n] + 1e-6f);
    float c = -prob + 5.f * bce + 5.f * dice;
    if (!isfinite(c)) c = 10000.f;
    out[(size_t)bq * NN + n] = c;
  }
}

extern "C" void kernel_launch(void* const* d_in, const int* in_sizes, int n_in,
                              void* d_out, int out_size, void* d_ws, size_t ws_size,
                              hipStream_t stream) {
  const float* pred_logits = (const float*)d_in[0];
  const float* pred_masks  = (const float*)d_in[1];
  const int*   gt_classes  = (const int*)d_in[2];
  const float* gt_masks    = (const float*)d_in[3];
  float* out = (float*)d_out;

  // workspace: ~31 MB
  __bf16* pD = (__bf16*)d_ws;
  __bf16* pS = pD + (size_t)BB * QT7 * SS * 1024;
  float* pQs = (float*)(pS + (size_t)BB * QT7 * SS * 1024);
  float* pT = pQs + (size_t)BB * QT7 * 32 * SS * 2;
  float* tsum = pT + (size_t)BB * SS * NN;

  main_kernel<<<dim3(SS / WPB, QT7, BB), WPB * 64, 0, stream>>>(
      pred_masks, gt_masks, pD, pS, pQs, pT);
  treduce_kernel<<<BB, 64, 0, stream>>>(pT, tsum);
  combine_kernel<<<BB * QQ, 256, 0, stream>>>(pred_logits, gt_classes, pD, pS, pQs,
                                              tsum, out);
}

// Round 9
// 83.405 us; speedup vs baseline: 4.5775x; 2.8546x over previous
//
#include <hip/hip_runtime.h>
#include <math.h>

#define BB 4
#define QQ 200
#define NN 32
#define HWV 65536
#define NCLS 80
#define QT7 7           // ceil(200/32) q-tiles of 32
#define LN2 0.69314718055995f
#define SS 256          // k-slices per (b, qt)
#define CHUNKK 256      // k per wave
#define NH 8            // half-steps per wave (32 k each)
#define WPB 4           // waves per block (independent k-slices, no barriers)
#define LDH 72          // bf16 per LDS row: 64 data + 8 pad -> 144B stride (measured 0 conflicts)

typedef __bf16 bf16x8 __attribute__((ext_vector_type(8)));
typedef __bf16 bf16x4 __attribute__((ext_vector_type(4)));
typedef float f32x16 __attribute__((ext_vector_type(16)));
typedef float f32x4 __attribute__((ext_vector_type(4)));

__device__ __forceinline__ float bflo(unsigned u) {
  union { unsigned i; float f; } c; c.i = u << 16; return c.f;
}
__device__ __forceinline__ float bfhi(unsigned u) {
  union { unsigned i; float f; } c; c.i = u & 0xffff0000u; return c.f;
}

// ---------------- main MFMA kernel, half-tile reg->LDS staged ----------------
// grid (SS/WPB, QT7, BB), 256 threads. Each wave = one k-slice of 256 for a
// 32q x 32n tile; waves fully independent (no __syncthreads).
// Half-step pipeline: stage 32k (av/tv[4] = 32 regs), issue next 8 loads,
// compute 2 MFMA k-steps. Live set ~100 VGPR + 32 acc -> fits 128, NO SPILLS
// (r7/r8 full-tile prefetch held 64 staging regs -> spilled at 84/128 alloc).
__global__ __launch_bounds__(256, 2) void main_kernel(
    const float* __restrict__ pred_masks, const float* __restrict__ gt_masks,
    __bf16* __restrict__ pD, __bf16* __restrict__ pS, float* __restrict__ pQs,
    float* __restrict__ pT) {
  __shared__ __bf16 xls[WPB][32][LDH];   // 4.6 KB/wave
  __shared__ __bf16 tls[WPB][32][LDH];   // 4.6 KB/wave

  const int tid = threadIdx.x;
  const int w = tid >> 6, lane = tid & 63;
  const int sIdx = blockIdx.x * WPB + w;
  const int qt = blockIdx.y, b = blockIdx.z;
  const int rc = lane & 31, half = lane >> 5;
  const int l8r = lane >> 3, l8c = lane & 7;   // staging: 8 rows x 8 chunks(16B)
  const bool doT = (qt == 0);
  const int k0 = sIdx * CHUNKK;

  // byte offsets: row stride = HWV*4B = 1<<18
  const char* baseA = (const char*)(pred_masks + (size_t)b * QQ * HWV + k0) + l8c * 16;
  const char* baseT = (const char*)(gt_masks + (size_t)b * NN * HWV + k0) + l8c * 16;
  unsigned aoff[4], toff[4];
#pragma unroll
  for (int i = 0; i < 4; ++i) {
    int ar = qt * 32 + 8 * i + l8r;
    if (ar > QQ - 1) ar = QQ - 1;        // pad rows duplicate row 199 (discarded)
    aoff[i] = (unsigned)ar << 18;
    toff[i] = (unsigned)(8 * i + l8r) << 18;
  }

  f32x16 accD, accS;
#pragma unroll
  for (int r = 0; r < 16; ++r) { accD[r] = 0.f; accS[r] = 0.f; }
  float ssum = 0.f, xsum = 0.f, lgsum = 0.f, tsl = 0.f;

  f32x4 av[4], tv[4];
  auto LOADH = [&](int h) {
#pragma unroll
    for (int i = 0; i < 4; ++i)
      av[i] = __builtin_nontemporal_load(
          reinterpret_cast<const f32x4*>(baseA + aoff[i] + h * 128));
#pragma unroll
    for (int i = 0; i < 4; ++i)
      tv[i] = *reinterpret_cast<const f32x4*>(baseT + toff[i] + h * 128);
  };

  char* xb = (char*)&xls[w][0][0];
  char* tb = (char*)&tls[w][0][0];

  LOADH(0);
#pragma unroll
  for (int h = 0; h < NH; ++h) {
    const int sub = (h & 1) * 64;   // which 64B half of the 144B row
    // ---- stage current half (consumes av/tv via reg-dependency waits) ----
#pragma unroll
    for (int i = 0; i < 4; ++i) {
      int row = 8 * i + l8r;
      f32x4 x = av[i];
      bf16x4 xv = {(__bf16)x.x, (__bf16)x.y, (__bf16)x.z, (__bf16)x.w};
      *reinterpret_cast<bf16x4*>(xb + row * 144 + sub + l8c * 8) = xv;
      f32x4 t = tv[i];
      bf16x4 tv4 = {(__bf16)t.x, (__bf16)t.y, (__bf16)t.z, (__bf16)t.w};
      *reinterpret_cast<bf16x4*>(tb + row * 144 + sub + l8c * 8) = tv4;
      if (doT) tsl += (t.x + t.y) + (t.z + t.w);   // exact f32 t-sums at stage
    }
    // ---- reissue loads for next half (in flight during compute) ----
    if (h + 1 < NH) LOADH(h + 1);
    // ---- fragments + transform + MFMA (same-wave DS ordering is in-order) ----
#pragma unroll
    for (int ks2 = 0; ks2 < 2; ++ks2) {
      int off = rc * 144 + sub + ks2 * 32 + half * 16;
      bf16x8 xf = *reinterpret_cast<const bf16x8*>(xb + off);
      bf16x8 tf = *reinterpret_cast<const bf16x8*>(tb + off);
      bf16x8 sf;
      float p0 = 1.f, p1 = 1.f;
#pragma unroll
      for (int j = 0; j < 8; ++j) {
        float x = (float)xf[j];
        float e = __expf(-x);                  // |x| <~ 6 for N(0,1) inputs
        float a = 1.f + e;
        float s = __builtin_amdgcn_rcpf(a);    // sigmoid(x)
        sf[j] = (__bf16)s;
        ssum += s;
        xsum += x;
        if (j < 4) p0 *= a; else p1 *= a;      // two chains for ILP
      }
      lgsum += __log2f(p0 * p1);               // prod8 < 3e20, fp32-safe
      accD = __builtin_amdgcn_mfma_f32_32x32x16_bf16(xf, tf, accD, 0, 0, 0);
      accS = __builtin_amdgcn_mfma_f32_32x32x16_bf16(sf, tf, accS, 0, 0, 0);
    }
  }

  // lanes l, l^32 hold the two k-halves of row rc
  ssum += __shfl_xor(ssum, 32);
  xsum += __shfl_xor(xsum, 32);
  lgsum += __shfl_xor(lgsum, 32);

  const size_t tile32 = (size_t)(b * QT7 + qt);
  if (lane < 32) {
    float* pq = pQs + ((tile32 * 32 + rc) * (size_t)SS + sIdx) * 2;
    pq[0] = ssum;                       // sum of sigmoid over slice
    pq[1] = -xsum - LN2 * lgsum;        // sum of log(1-sigmoid)
  }
  if (doT) {
    // tsl held per staging lane: rows 8i+l8r summed over chunks l8c.
    // reduce across the 8 chunk-lanes of each row group
#pragma unroll
    for (int m = 1; m <= 4; m <<= 1) tsl += __shfl_xor(tsl, m);
    // lane pattern: lanes with l8c==0 hold row-group sums for rows {l8r, 8+l8r, 16+l8r, 24+l8r}
    // Wait -- tsl accumulated over all i (4 row-groups) in one scalar: it holds
    // the sum over rows {l8r, 8+l8r, 16+l8r, 24+l8r}. That is NOT per-row.
    // Per-row t sums are required. Recompute per-row via 4 separate lanesums
    // is not available here, so fall back: lanes 0..7 (l8r 0..7) hold 4-row
    // bundle sums; we need per (b,n) sums -> do it in treduce from pT bundles.
    if ((lane & 7) == 0) {
      // store bundle sums: index by l8r (8 bundles of 4 rows each)
      pT[((size_t)b * SS + sIdx) * NN + l8r] = tsl;
    }
  }
#pragma unroll
  for (int r = 0; r < 16; ++r) {
    int row = (r & 3) + 8 * (r >> 2) + 4 * half;   // verified C/D map
    size_t o = ((tile32 * 32 + row) * (size_t)SS + sIdx) * 32 + rc;  // [q][s][n]
    pD[o] = (__bf16)accD[r];
    pS[o] = (__bf16)accS[r];
  }
}

// ---------------- t column sums, standalone (bundle trick above is lossy  ----
// ---- for per-row sums, so compute tsum directly: 128 rows, trivial cost) ----
__global__ __launch_bounds__(256) void tsum_kernel(const float* __restrict__ gt,
                                                   float* __restrict__ tsum) {
  int bn = blockIdx.x;  // 0..B*N-1
  const float* p = gt + (size_t)bn * HWV;
  float acc = 0.f;
  for (int k = threadIdx.x * 4; k < HWV; k += 256 * 4) {
    f32x4 v = *reinterpret_cast<const f32x4*>(p + k);
    acc += (v.x + v.y) + (v.z + v.w);
  }
#pragma unroll
  for (int m = 1; m < 64; m <<= 1) acc += __shfl_xor(acc, m);
  __shared__ float wsum[4];
  if ((threadIdx.x & 63) == 0) wsum[threadIdx.x >> 6] = acc;
  __syncthreads();
  if (threadIdx.x == 0) tsum[bn] = (wsum[0] + wsum[1]) + (wsum[2] + wsum[3]);
}

// ---------------- reduce + combine ----------------
__global__ __launch_bounds__(256) void combine_kernel(
    const float* __restrict__ pred_logits, const int* __restrict__ gt_classes,
    const __bf16* __restrict__ pD, const __bf16* __restrict__ pS,
    const float* __restrict__ pQs, const float* __restrict__ tsum,
    float* __restrict__ out) {
  __shared__ float redD[32][33];
  __shared__ float redS[32][33];
  __shared__ float redQ[4][2];
  int bq = blockIdx.x;
  int b = bq / QQ, q = bq % QQ;
  int qt = q >> 5, qi = q & 31;
  int tid = threadIdx.x;
  int sg = tid >> 3, nq = tid & 7;  // 32 s-groups x 8 n-quads
  size_t rowbase = ((size_t)(b * QT7 + qt) * 32 + qi) * (size_t)SS;
  float dD[4] = {0.f, 0.f, 0.f, 0.f}, dS4[4] = {0.f, 0.f, 0.f, 0.f};
  for (int s = sg; s < SS; s += 32) {
    size_t o = (rowbase + s) * 32 + nq * 4;
    uint2 ud = *reinterpret_cast<const uint2*>(pD + o);
    uint2 us = *reinterpret_cast<const uint2*>(pS + o);
    dD[0] += bflo(ud.x); dD[1] += bfhi(ud.x); dD[2] += bflo(ud.y); dD[3] += bfhi(ud.y);
    dS4[0] += bflo(us.x); dS4[1] += bfhi(us.x); dS4[2] += bflo(us.y); dS4[3] += bfhi(us.y);
  }
#pragma unroll
  for (int j = 0; j < 4; ++j) {
    redD[sg][nq * 4 + j] = dD[j];
    redS[sg][nq * 4 + j] = dS4[j];
  }
  float sS = 0.f, sL = 0.f;
  for (int s = tid; s < SS; s += 256) {
    const float* pq = pQs + (rowbase + s) * 2;
    sS += pq[0];
    sL += pq[1];
  }
#pragma unroll
  for (int m = 1; m < 64; m <<= 1) { sS += __shfl_xor(sS, m); sL += __shfl_xor(sL, m); }
  if ((tid & 63) == 0) { redQ[tid >> 6][0] = sS; redQ[tid >> 6][1] = sL; }
  __syncthreads();
  if (tid < 32) {
    int n = tid;
    float tD = 0.f, tS = 0.f;
#pragma unroll 8
    for (int g = 0; g < 32; ++g) { tD += redD[g][n]; tS += redS[g][n]; }
    float fsS = (redQ[0][0] + redQ[1][0]) + (redQ[2][0] + redQ[3][0]);
    float fsL = (redQ[0][1] + redQ[1][1]) + (redQ[2][1] + redQ[3][1]);
    int cls = gt_classes[b * NN + n];
    float logit = pred_logits[((size_t)(b * QQ + q)) * NCLS + cls];
    float prob = 1.f / (1.f + __expf(-logit));
    float bce = -(tD + fsL) * (1.f / (float)HWV);
    float dice = 1.f - 2.f * tS / (fsS + tsum[b * NN + n] + 1e-6f);
    float c = -prob + 5.f * bce + 5.f * dice;
    if (!isfinite(c)) c = 10000.f;
    out[(size_t)bq * NN + n] = c;
  }
}

extern "C" void kernel_launch(void* const* d_in, const int* in_sizes, int n_in,
                              void* d_out, int out_size, void* d_ws, size_t ws_size,
                              hipStream_t stream) {
  const float* pred_logits = (const float*)d_in[0];
  const float* pred_masks  = (const float*)d_in[1];
  const int*   gt_classes  = (const int*)d_in[2];
  const float* gt_masks    = (const float*)d_in[3];
  float* out = (float*)d_out;

  // workspace: ~31 MB
  __bf16* pD = (__bf16*)d_ws;
  __bf16* pS = pD + (size_t)BB * QT7 * SS * 1024;
  float* pQs = (float*)(pS + (size_t)BB * QT7 * SS * 1024);
  float* pT = pQs + (size_t)BB * QT7 * 32 * SS * 2;   // unused this round
  float* tsum = pT + (size_t)BB * SS * NN;

  main_kernel<<<dim3(SS / WPB, QT7, BB), WPB * 64, 0, stream>>>(
      pred_masks, gt_masks, pD, pS, pQs, pT);
  tsum_kernel<<<BB * NN, 256, 0, stream>>>(gt_masks, tsum);
  combine_kernel<<<BB * QQ, 256, 0, stream>>>(pred_logits, gt_classes, pD, pS, pQs,
                                              tsum, out);
}